// Round 13
// baseline (117.296 us; speedup 1.0000x reference)
//
#include <hip/hip_runtime.h>

#define NN 50000
#define CC 128
#define OC 64
#define EE 800000
#define NBKT 196      // buckets of 256 nodes
#define CAP 8192      // padded per-bucket capacity (mean ~4096 + align pad)
#define CHUNK 4096
#define NBIN_BLK 196  // ceil(EE/CHUNK)

typedef __attribute__((ext_vector_type(8))) short short8;
typedef __attribute__((ext_vector_type(4))) float f32x4;
typedef __attribute__((ext_vector_type(2))) float f32x2;

__device__ __forceinline__ ushort f2bf(float x) {
    uint u = __float_as_uint(x);
    return (ushort)((u + 0x7fffu + ((u >> 16) & 1u)) >> 16);
}

// decode 8 fp8 (two uints) and accumulate into a[0..7]
__device__ __forceinline__ void acc8_fp8(uint vx, uint vy, float* a) {
    f32x2 p0 = __builtin_amdgcn_cvt_pk_f32_fp8(vx, false);
    f32x2 p1 = __builtin_amdgcn_cvt_pk_f32_fp8(vx, true);
    f32x2 p2 = __builtin_amdgcn_cvt_pk_f32_fp8(vy, false);
    f32x2 p3 = __builtin_amdgcn_cvt_pk_f32_fp8(vy, true);
    a[0] += p0[0]; a[1] += p0[1]; a[2] += p1[0]; a[3] += p1[1];
    a[4] += p2[0]; a[5] += p2[1]; a[6] += p3[0]; a[7] += p3[1];
}

__device__ __forceinline__ uint enc4_fp8(float x, float y, float z, float w) {
    uint u = 0;
    u = __builtin_amdgcn_cvt_pk_fp8_f32(x, y, u, false);
    u = __builtin_amdgcn_cvt_pk_fp8_f32(z, w, u, true);
    return u;
}

// unsigned clamp: garbage (e.g. 0xAA poison) clamps to a valid row id
__device__ __forceinline__ uint uclamp(uint v) {
    return v < (uint)(NN - 1) ? v : (uint)(NN - 1);
}

// ---------------- fine sort within bucket -> per-node [start,end) ----------------
// Node segment starts padded to multiples of 4 ints (16B) for aligned uint4 loads.
__global__ __launch_bounds__(256) void k_fine(const int* __restrict__ gcnt,
                                              const uint* __restrict__ binned,
                                              int* __restrict__ offs,
                                              int* __restrict__ offe,
                                              int* __restrict__ ssrc) {
    __shared__ int hist[256];
    __shared__ int sc[256];
    __shared__ int curs[256];
    int b = blockIdx.x, tid = threadIdx.x;
    int s = b * CAP, cnt = gcnt[b];
    hist[tid] = 0;
    __syncthreads();
    for (int i = tid; i < cnt; i += 256) atomicAdd(&hist[binned[s + i] >> 16], 1);
    __syncthreads();
    int v = hist[tid];
    int v4 = (v + 3) & ~3;          // aligned segment size
    sc[tid] = v4;
    __syncthreads();
    for (int d = 1; d < 256; d <<= 1) {
        int t = (tid >= d) ? sc[tid - d] : 0;
        __syncthreads();
        sc[tid] += t;
        __syncthreads();
    }
    int excl = sc[tid] - v4;        // aligned start (multiple of 4)
    int idx = b * 256 + tid;
    if (idx < NN) { offs[idx] = s + excl; offe[idx] = s + excl + v; }
    curs[tid] = excl;
    __syncthreads();
    for (int i = tid; i < cnt; i += 256) {
        uint p = binned[s + i];
        int r = atomicAdd(&curs[p >> 16], 1);
        ssrc[s + r] = (int)(p & 0xffffu);
    }
}

// ---------------- combined prep + bin (independent work, one dispatch) ----------------
__device__ __forceinline__ void packw_body(const float* __restrict__ Wl,
                                           const float* __restrict__ Wr,
                                           ushort* __restrict__ wp, int t) {
    int l = t & 63, n = (t >> 6) & 7, ks = t >> 9;
    int kg = l >> 4, col = 16 * n + (l & 15);
    uint out[4];
#pragma unroll
    for (int jj = 0; jj < 4; ++jj) {
        int k = 32 * ks + 8 * kg + 2 * jj;
        float v0 = (k < 128) ? Wl[k * 128 + col] : Wr[(k - 128) * 128 + col];
        float v1 = (k + 1 < 128) ? Wl[(k + 1) * 128 + col] : Wr[(k + 1 - 128) * 128 + col];
        out[jj] = (uint)f2bf(v0) | ((uint)f2bf(v1) << 16);
    }
    *(uint4*)(wp + (long long)t * 8) = make_uint4(out[0], out[1], out[2], out[3]);
}

__global__ __launch_bounds__(256) void k_prep_bin(
    const float* __restrict__ x, ushort* __restrict__ xb, unsigned char* __restrict__ x8,
    const float* __restrict__ W1l, const float* __restrict__ W1r, ushort* __restrict__ wp1,
    const float* __restrict__ W2l, const float* __restrict__ W2r, ushort* __restrict__ wp2,
    const float* __restrict__ Wc, ushort* __restrict__ wpc,
    const int* __restrict__ src, const int* __restrict__ dst,
    int* __restrict__ gcnt, uint* __restrict__ binned) {
    __shared__ int h[256];
    __shared__ int gb[256];
    __shared__ int cur[256];
    int b = blockIdx.x, tid = threadIdx.x;
    if (b < 6250) {
        int i = b * 256 + tid;  // NN*CC/4 = 1,600,000 exactly
        float4 v = ((const float4*)x)[i];
        ushort4 u;
        u.x = f2bf(v.x); u.y = f2bf(v.y); u.z = f2bf(v.z); u.w = f2bf(v.w);
        ((ushort4*)xb)[i] = u;
        ((uint*)x8)[i] = enc4_fp8(v.x, v.y, v.z, v.w);
    } else if (b < 6266) {
        packw_body(W1l, W1r, wp1, (b - 6250) * 256 + tid);
    } else if (b < 6282) {
        packw_body(W2l, W2r, wp2, (b - 6266) * 256 + tid);
    } else if (b < 6286) {
        int t = (b - 6282) * 256 + tid;  // < 1024
        int l = t & 63, n = (t >> 6) & 3, ks = t >> 8;
        int kg = l >> 4, col = 16 * n + (l & 15);
        uint out[4];
#pragma unroll
        for (int jj = 0; jj < 4; ++jj) {
            int k = 32 * ks + 8 * kg + 2 * jj;
            out[jj] = (uint)f2bf(Wc[k * 64 + col]) | ((uint)f2bf(Wc[(k + 1) * 64 + col]) << 16);
        }
        *(uint4*)(wpc + (long long)t * 8) = make_uint4(out[0], out[1], out[2], out[3]);
    } else {
        // ---- bin role: blocks [6286, 6286+NBIN_BLK) ----
        int bb = b - 6286;
        h[tid] = 0;
        __syncthreads();
        int e0 = bb * CHUNK;
        int dreg[16];
#pragma unroll
        for (int it = 0; it < 16; ++it) {
            int e = e0 + tid + it * 256;
            dreg[it] = (e < EE) ? dst[e] : -1;
            if (dreg[it] >= 0) atomicAdd(&h[dreg[it] >> 8], 1);
        }
        __syncthreads();
        if (tid < NBKT) {
            gb[tid] = h[tid] ? (tid * CAP + atomicAdd(&gcnt[tid], h[tid])) : 0;
            cur[tid] = 0;
        }
        __syncthreads();
#pragma unroll
        for (int it = 0; it < 16; ++it) {
            int e = e0 + tid + it * 256;
            int d = dreg[it];
            if (d >= 0) {
                int bk = d >> 8;
                int r = atomicAdd(&cur[bk], 1);
                binned[gb[bk] + r] = ((uint)(d & 255) << 16) | (uint)src[e];
            }
        }
    }
}

// ---------------- gather (fp8) into LDS: 2 x 8-lane groups per node ----------------
// 512 threads = 64 groups; node r handled by groups 2r (even 8-edge chunks) and
// 2r+1 (odd chunks). Each lane owns 16 contiguous channels (uint4 = 16 fp8);
// one wave load instruction fetches 8 different rows. Partials combined via pf32.
__device__ __forceinline__ void gather_stage32(
    const int* __restrict__ offs, const int* __restrict__ offe,
    const int* __restrict__ ssrc, const unsigned char* __restrict__ x8,
    const ushort* __restrict__ xbf,
    char* a_sh, float* pf32, int row0, int tid) {
    int grp = tid >> 3;      // 0..63
    int l7 = tid & 7;        // channels 16*l7 .. 16*l7+15
    int r = grp >> 1;        // node row 0..31
    int half = grp & 1;
    int node = row0 + r;
    int s0 = 0, s1 = 0;
    if (node < NN) { s0 = offs[node]; s1 = offe[node]; }
    float a[16];
#pragma unroll
    for (int k = 0; k < 16; ++k) a[k] = 0.f;
    int j = s0 + 8 * half;   // alternating 8-edge chunks; stays 16B-aligned
    if (j < s1) {
        // over-reads stay inside the bucket's CAP segment; garbage clamped+masked.
        uint4 iA = *(const uint4*)(ssrc + j);
        uint4 iB = *(const uint4*)(ssrc + j + 4);
        do {
            uint4 nA = *(const uint4*)(ssrc + j + 16);   // prefetch next chunk
            uint4 nB = *(const uint4*)(ssrc + j + 20);
            uint4 v0 = ((const uint4*)(x8 + (long long)uclamp(iA.x) * CC))[l7];
            uint4 v1 = ((const uint4*)(x8 + (long long)uclamp(iA.y) * CC))[l7];
            uint4 v2 = ((const uint4*)(x8 + (long long)uclamp(iA.z) * CC))[l7];
            uint4 v3 = ((const uint4*)(x8 + (long long)uclamp(iA.w) * CC))[l7];
            uint4 v4 = ((const uint4*)(x8 + (long long)uclamp(iB.x) * CC))[l7];
            uint4 v5 = ((const uint4*)(x8 + (long long)uclamp(iB.y) * CC))[l7];
            uint4 v6 = ((const uint4*)(x8 + (long long)uclamp(iB.z) * CC))[l7];
            uint4 v7 = ((const uint4*)(x8 + (long long)uclamp(iB.w) * CC))[l7];
            int rem = s1 - j;
            { uint m = rem > 0 ? 0xffffffffu : 0u;
              acc8_fp8(v0.x & m, v0.y & m, a); acc8_fp8(v0.z & m, v0.w & m, a + 8); }
            { uint m = rem > 1 ? 0xffffffffu : 0u;
              acc8_fp8(v1.x & m, v1.y & m, a); acc8_fp8(v1.z & m, v1.w & m, a + 8); }
            { uint m = rem > 2 ? 0xffffffffu : 0u;
              acc8_fp8(v2.x & m, v2.y & m, a); acc8_fp8(v2.z & m, v2.w & m, a + 8); }
            { uint m = rem > 3 ? 0xffffffffu : 0u;
              acc8_fp8(v3.x & m, v3.y & m, a); acc8_fp8(v3.z & m, v3.w & m, a + 8); }
            { uint m = rem > 4 ? 0xffffffffu : 0u;
              acc8_fp8(v4.x & m, v4.y & m, a); acc8_fp8(v4.z & m, v4.w & m, a + 8); }
            { uint m = rem > 5 ? 0xffffffffu : 0u;
              acc8_fp8(v5.x & m, v5.y & m, a); acc8_fp8(v5.z & m, v5.w & m, a + 8); }
            { uint m = rem > 6 ? 0xffffffffu : 0u;
              acc8_fp8(v6.x & m, v6.y & m, a); acc8_fp8(v6.z & m, v6.w & m, a + 8); }
            { uint m = rem > 7 ? 0xffffffffu : 0u;
              acc8_fp8(v7.x & m, v7.y & m, a); acc8_fp8(v7.z & m, v7.w & m, a + 8); }
            iA = nA; iB = nB;
            j += 16;
        } while (j < s1);
    }
    // combine halves: odd group stores partial, even group adds + writes LDS
    if (half == 1) {
#pragma unroll
        for (int q = 0; q < 4; ++q)
            *(float4*)(pf32 + r * 128 + l7 * 16 + q * 4) =
                make_float4(a[4 * q], a[4 * q + 1], a[4 * q + 2], a[4 * q + 3]);
    }
    __syncthreads();
    if (half == 0) {
#pragma unroll
        for (int q = 0; q < 4; ++q) {
            float4 p = *(const float4*)(pf32 + r * 128 + l7 * 16 + q * 4);
            a[4 * q] += p.x; a[4 * q + 1] += p.y; a[4 * q + 2] += p.z; a[4 * q + 3] += p.w;
        }
        float dinv = 1.0f / fmaxf((float)(s1 - s0), 1.0f);
        uint4 o0, o1;
        o0.x = (uint)f2bf(a[0] * dinv)  | ((uint)f2bf(a[1] * dinv)  << 16);
        o0.y = (uint)f2bf(a[2] * dinv)  | ((uint)f2bf(a[3] * dinv)  << 16);
        o0.z = (uint)f2bf(a[4] * dinv)  | ((uint)f2bf(a[5] * dinv)  << 16);
        o0.w = (uint)f2bf(a[6] * dinv)  | ((uint)f2bf(a[7] * dinv)  << 16);
        o1.x = (uint)f2bf(a[8] * dinv)  | ((uint)f2bf(a[9] * dinv)  << 16);
        o1.y = (uint)f2bf(a[10] * dinv) | ((uint)f2bf(a[11] * dinv) << 16);
        o1.z = (uint)f2bf(a[12] * dinv) | ((uint)f2bf(a[13] * dinv) << 16);
        o1.w = (uint)f2bf(a[14] * dinv) | ((uint)f2bf(a[15] * dinv) << 16);
        int c0 = 2 * l7;
        *(uint4*)(a_sh + r * 512 + ((c0 * 16) ^ ((r & 7) << 4))) = o0;
        *(uint4*)(a_sh + r * 512 + (((c0 + 1) * 16) ^ ((r & 7) << 4))) = o1;
    }
    // stage self rows (bf16, linear): 32 rows x 16 chunks = 512 = one per thread
    {
        int rr = tid >> 4, c = tid & 15;
        int row = row0 + rr;
        uint4 v = make_uint4(0, 0, 0, 0);
        if (row < NN) v = ((const uint4*)(xbf + (long long)row * CC))[c];
        *(uint4*)(a_sh + rr * 512 + ((256 + c * 16) ^ ((rr & 7) << 4))) = v;
    }
}

// ---------------- fused gather + MFMA layer (BM=32, 8 waves: 2r x 4c) ----------------
__global__ __launch_bounds__(512) void k_fused_layer(
    const int* __restrict__ offs, const int* __restrict__ offe,
    const int* __restrict__ ssrc, const unsigned char* __restrict__ x8,
    const ushort* __restrict__ xbf,
    const ushort* __restrict__ wp, const float* __restrict__ bias,
    ushort* __restrict__ hbf, unsigned char* __restrict__ h8) {
    __shared__ uint4 a_sh4[1024];   // 16KB
    __shared__ float pf32[4096];    // 16KB partial buffer
    char* a_sh = (char*)a_sh4;
    int row0 = blockIdx.x * 32;
    int tid = threadIdx.x;
    gather_stage32(offs, offe, ssrc, x8, xbf, a_sh, pf32, row0, tid);
    __syncthreads();

    int w = tid >> 6, l = tid & 63;
    int l15 = l & 15, kg = l >> 4;
    int wr = w >> 2, wc = w & 3;      // wave: rows 16*wr.., cols 32*wc..
    int lrow = 16 * wr + l15;
    f32x4 acc[2];
#pragma unroll
    for (int n = 0; n < 2; ++n) {
        float b = bias[16 * (2 * wc + n) + l15];
        acc[n] = (f32x4){b, b, b, b};
    }
#pragma unroll
    for (int ks = 0; ks < 8; ++ks) {
        short8 af = *(const short8*)(a_sh + lrow * 512 + ((ks * 64 + kg * 16) ^ ((lrow & 7) << 4)));
#pragma unroll
        for (int n = 0; n < 2; ++n) {
            short8 bf = ((const short8*)wp)[(ks * 8 + 2 * wc + n) * 64 + l];
            acc[n] = __builtin_amdgcn_mfma_f32_16x16x32_bf16(af, bf, acc[n], 0, 0, 0);
        }
    }
#pragma unroll
    for (int n = 0; n < 2; ++n) {
        int col = 16 * (2 * wc + n) + l15;
#pragma unroll
        for (int r = 0; r < 4; ++r) {
            int row = row0 + 16 * wr + kg * 4 + r;
            if (row < NN) {
                float v = fmaxf(acc[n][r], 0.f);
                hbf[(long long)row * CC + col] = f2bf(v);
                h8[(long long)row * CC + col] =
                    (unsigned char)(__builtin_amdgcn_cvt_pk_fp8_f32(v, v, 0u, false) & 0xffu);
            }
        }
    }
}

// ---------------- fused gather + MFMA layer2 + classifier (BM=32, 8 waves) ----------------
__global__ __launch_bounds__(512) void k_fused_layer2_cls(
    const int* __restrict__ offs, const int* __restrict__ offe,
    const int* __restrict__ ssrc, const unsigned char* __restrict__ h8,
    const ushort* __restrict__ xbf,
    const ushort* __restrict__ wp2, const float* __restrict__ b2,
    const ushort* __restrict__ wpc, const float* __restrict__ bc,
    float* __restrict__ h2f, float* __restrict__ logits) {
    __shared__ uint4 a_sh4[1024];   // 16KB
    __shared__ float pf32[4096];    // 16KB
    char* a_sh = (char*)a_sh4;
    int row0 = blockIdx.x * 32;
    int tid = threadIdx.x;
    gather_stage32(offs, offe, ssrc, h8, xbf, a_sh, pf32, row0, tid);
    __syncthreads();

    int w = tid >> 6, l = tid & 63;
    int l15 = l & 15, kg = l >> 4;
    int wr = w >> 2, wc = w & 3;
    int lrow = 16 * wr + l15;
    f32x4 acc[2];
#pragma unroll
    for (int n = 0; n < 2; ++n) {
        float b = b2[16 * (2 * wc + n) + l15];
        acc[n] = (f32x4){b, b, b, b};
    }
#pragma unroll
    for (int ks = 0; ks < 8; ++ks) {
        short8 af = *(const short8*)(a_sh + lrow * 512 + ((ks * 64 + kg * 16) ^ ((lrow & 7) << 4)));
#pragma unroll
        for (int n = 0; n < 2; ++n) {
            short8 bf = ((const short8*)wp2)[(ks * 8 + 2 * wc + n) * 64 + l];
            acc[n] = __builtin_amdgcn_mfma_f32_16x16x32_bf16(af, bf, acc[n], 0, 0, 0);
        }
    }
    __syncthreads();

    // epilogue: relu -> h2 f32 (global) + bf16 into cls LDS [32][256B] swizzled
#pragma unroll
    for (int n = 0; n < 2; ++n) {
        int col = 16 * (2 * wc + n) + l15;
#pragma unroll
        for (int r = 0; r < 4; ++r) {
            int lr = 16 * wr + kg * 4 + r;
            int row = row0 + lr;
            float v = fmaxf(acc[n][r], 0.f);
            if (row < NN) h2f[(long long)row * CC + col] = v;
            *(ushort*)(a_sh + lr * 256 + ((col * 2) ^ ((lr & 7) << 4))) = f2bf(v);
        }
    }
    __syncthreads();

    // classifier: logits = h2 @ Wc + bc (K=128, N=64); wave covers 16 cols
    int wc2 = w & 3;
    f32x4 acc2;
    {
        float b = bc[16 * wc2 + l15];
        acc2 = (f32x4){b, b, b, b};
    }
#pragma unroll
    for (int ks = 0; ks < 4; ++ks) {
        short8 af = *(const short8*)(a_sh + lrow * 256 + ((ks * 64 + kg * 16) ^ ((lrow & 7) << 4)));
        short8 bf = ((const short8*)wpc)[(ks * 4 + wc2) * 64 + l];
        acc2 = __builtin_amdgcn_mfma_f32_16x16x32_bf16(af, bf, acc2, 0, 0, 0);
    }
    {
        int col = 16 * wc2 + l15;
#pragma unroll
        for (int r = 0; r < 4; ++r) {
            int row = row0 + 16 * wr + kg * 4 + r;
            if (row < NN) logits[(long long)row * OC + col] = acc2[r];
        }
    }
}

extern "C" void kernel_launch(void* const* d_in, const int* in_sizes, int n_in,
                              void* d_out, int out_size, void* d_ws, size_t ws_size,
                              hipStream_t stream) {
    const float* x_doc = (const float*)d_in[0];
    const int* ei = (const int*)d_in[2];
    const float* W1l = (const float*)d_in[4];
    const float* b1  = (const float*)d_in[5];
    const float* W1r = (const float*)d_in[6];
    const float* W2l = (const float*)d_in[7];
    const float* b2  = (const float*)d_in[8];
    const float* W2r = (const float*)d_in[9];
    const float* Wc  = (const float*)d_in[10];
    const float* bc  = (const float*)d_in[11];

    const int* src = ei;
    const int* dst = ei + EE;

    // workspace layout (16B-aligned segments)
    ushort* x_bf  = (ushort*)d_ws;                       // NN*CC ushort
    ushort* h1_bf = x_bf + (long long)NN * CC;           // NN*CC ushort
    unsigned char* x_f8  = (unsigned char*)(h1_bf + (long long)NN * CC);  // NN*CC bytes
    unsigned char* h1_f8 = x_f8 + (long long)NN * CC;    // NN*CC bytes
    ushort* wp1   = (ushort*)(h1_f8 + (long long)NN * CC); // 32768
    ushort* wp2   = wp1 + 32768;                         // 32768
    ushort* wpc   = wp2 + 32768;                         // 8192
    int* gcnt     = (int*)(wpc + 8192);                  // 256
    int* offs     = gcnt + 256;                          // NN (pad to 50176)
    int* offe     = offs + 50176;                        // NN (pad to 50176)
    int* ssrc     = offe + 50176;                        // NBKT*CAP
    uint* binned  = (uint*)(ssrc + NBKT * CAP);          // NBKT*CAP

    float* logits = (float*)d_out;                       // NN*OC
    float* h2f    = logits + (long long)NN * OC;         // NN*CC

    // zero bucket counters, then combined prep+bin -> fine
    hipMemsetAsync(gcnt, 0, 256 * sizeof(int), stream);
    k_prep_bin<<<6286 + NBIN_BLK, 256, 0, stream>>>(x_doc, x_bf, x_f8, W1l, W1r, wp1,
                                                    W2l, W2r, wp2, Wc, wpc,
                                                    src, dst, gcnt, binned);
    k_fine<<<NBKT, 256, 0, stream>>>(gcnt, binned, offs, offe, ssrc);

    // layer 1 (fp8 gather fused)
    k_fused_layer<<<(NN + 31) / 32, 512, 0, stream>>>(offs, offe, ssrc, x_f8, x_bf,
                                                      wp1, b1, h1_bf, h1_f8);

    // layer 2 + classifier (fp8 gather fused)
    k_fused_layer2_cls<<<(NN + 31) / 32, 512, 0, stream>>>(offs, offe, ssrc, h1_f8, h1_bf,
                                                           wp2, b2, wpc, bc, h2f, logits);
}

// Round 14
// 98.070 us; speedup vs baseline: 1.1960x; 1.1960x over previous
//
#include <hip/hip_runtime.h>

#define NN 50000
#define CC 128
#define OC 64
#define EE 800000
#define NBKT 196      // buckets of 256 nodes
#define CAP 8192      // padded per-bucket capacity (mean 4096 + align pad <= ~5000)
#define CHUNK 4096
#define NBIN_BLK 196  // ceil(EE/CHUNK)

typedef __attribute__((ext_vector_type(8))) short short8;
typedef __attribute__((ext_vector_type(4))) float f32x4;
typedef __attribute__((ext_vector_type(2))) float f32x2;

__device__ __forceinline__ ushort f2bf(float x) {
    uint u = __float_as_uint(x);
    return (ushort)((u + 0x7fffu + ((u >> 16) & 1u)) >> 16);
}

// decode 8 fp8 (two uints) and accumulate into a[0..7]
__device__ __forceinline__ void acc8_fp8(uint vx, uint vy, float* a) {
    f32x2 p0 = __builtin_amdgcn_cvt_pk_f32_fp8(vx, false);
    f32x2 p1 = __builtin_amdgcn_cvt_pk_f32_fp8(vx, true);
    f32x2 p2 = __builtin_amdgcn_cvt_pk_f32_fp8(vy, false);
    f32x2 p3 = __builtin_amdgcn_cvt_pk_f32_fp8(vy, true);
    a[0] += p0[0]; a[1] += p0[1]; a[2] += p1[0]; a[3] += p1[1];
    a[4] += p2[0]; a[5] += p2[1]; a[6] += p3[0]; a[7] += p3[1];
}

__device__ __forceinline__ uint enc4_fp8(float x, float y, float z, float w) {
    uint u = 0;
    u = __builtin_amdgcn_cvt_pk_fp8_f32(x, y, u, false);
    u = __builtin_amdgcn_cvt_pk_fp8_f32(z, w, u, true);
    return u;
}

// unsigned clamp: garbage (e.g. 0xAAAAAAAA poison) clamps to NN-1, a valid row
__device__ __forceinline__ uint uclamp(uint v) {
    return v < (uint)(NN - 1) ? v : (uint)(NN - 1);
}

// ---------------- binning: one pass, padded bucket segments ----------------
__global__ __launch_bounds__(256) void k_bin(const int* __restrict__ src,
                                             const int* __restrict__ dst,
                                             int* __restrict__ gcnt,
                                             uint* __restrict__ binned) {
    __shared__ int h[256];
    __shared__ int gb[256];
    __shared__ int cur[256];
    int tid = threadIdx.x;
    h[tid] = 0;
    __syncthreads();
    int e0 = blockIdx.x * CHUNK;
    int dreg[16];
#pragma unroll
    for (int it = 0; it < 16; ++it) {
        int e = e0 + tid + it * 256;
        dreg[it] = (e < EE) ? dst[e] : -1;
        if (dreg[it] >= 0) atomicAdd(&h[dreg[it] >> 8], 1);
    }
    __syncthreads();
    if (tid < NBKT) {
        gb[tid] = h[tid] ? (tid * CAP + atomicAdd(&gcnt[tid], h[tid])) : 0;
        cur[tid] = 0;
    }
    __syncthreads();
#pragma unroll
    for (int it = 0; it < 16; ++it) {
        int e = e0 + tid + it * 256;
        int d = dreg[it];
        if (d >= 0) {
            int b = d >> 8;
            int r = atomicAdd(&cur[b], 1);
            binned[gb[b] + r] = ((uint)(d & 255) << 16) | (uint)src[e];
        }
    }
}

// ---------------- fine sort within bucket -> per-node [start,end) ----------------
// Node segment starts padded to multiples of 4 ints (16B) for aligned uint4 loads.
__global__ __launch_bounds__(256) void k_fine(const int* __restrict__ gcnt,
                                              const uint* __restrict__ binned,
                                              int* __restrict__ offs,
                                              int* __restrict__ offe,
                                              int* __restrict__ ssrc) {
    __shared__ int hist[256];
    __shared__ int sc[256];
    __shared__ int curs[256];
    int b = blockIdx.x, tid = threadIdx.x;
    int s = b * CAP, cnt = gcnt[b];
    hist[tid] = 0;
    __syncthreads();
    for (int i = tid; i < cnt; i += 256) atomicAdd(&hist[binned[s + i] >> 16], 1);
    __syncthreads();
    int v = hist[tid];
    int v4 = (v + 3) & ~3;          // aligned segment size
    sc[tid] = v4;
    __syncthreads();
    for (int d = 1; d < 256; d <<= 1) {
        int t = (tid >= d) ? sc[tid - d] : 0;
        __syncthreads();
        sc[tid] += t;
        __syncthreads();
    }
    int excl = sc[tid] - v4;        // aligned start (multiple of 4)
    int idx = b * 256 + tid;
    if (idx < NN) { offs[idx] = s + excl; offe[idx] = s + excl + v; }
    curs[tid] = excl;
    __syncthreads();
    for (int i = tid; i < cnt; i += 256) {
        uint p = binned[s + i];
        int r = atomicAdd(&curs[p >> 16], 1);
        ssrc[s + r] = (int)(p & 0xffffu);
    }
}

// ---------------- fused prep: gcnt zero + x->bf16/fp8 convert + weight packs ----------------
__device__ __forceinline__ void packw_body(const float* __restrict__ Wl,
                                           const float* __restrict__ Wr,
                                           ushort* __restrict__ wp, int t) {
    int l = t & 63, n = (t >> 6) & 7, ks = t >> 9;
    int kg = l >> 4, col = 16 * n + (l & 15);
    uint out[4];
#pragma unroll
    for (int jj = 0; jj < 4; ++jj) {
        int k = 32 * ks + 8 * kg + 2 * jj;
        float v0 = (k < 128) ? Wl[k * 128 + col] : Wr[(k - 128) * 128 + col];
        float v1 = (k + 1 < 128) ? Wl[(k + 1) * 128 + col] : Wr[(k + 1 - 128) * 128 + col];
        out[jj] = (uint)f2bf(v0) | ((uint)f2bf(v1) << 16);
    }
    *(uint4*)(wp + (long long)t * 8) = make_uint4(out[0], out[1], out[2], out[3]);
}

__global__ __launch_bounds__(256) void k_prep(
    const float* __restrict__ x, ushort* __restrict__ xb, unsigned char* __restrict__ x8,
    const float* __restrict__ W1l, const float* __restrict__ W1r, ushort* __restrict__ wp1,
    const float* __restrict__ W2l, const float* __restrict__ W2r, ushort* __restrict__ wp2,
    const float* __restrict__ Wc, ushort* __restrict__ wpc,
    int* __restrict__ gcnt) {
    int b = blockIdx.x, tid = threadIdx.x;
    if (b < 6250) {
        int i = b * 256 + tid;  // NN*CC/4 = 1,600,000 exactly
        float4 v = ((const float4*)x)[i];
        ushort4 u;
        u.x = f2bf(v.x); u.y = f2bf(v.y); u.z = f2bf(v.z); u.w = f2bf(v.w);
        ((ushort4*)xb)[i] = u;
        ((uint*)x8)[i] = enc4_fp8(v.x, v.y, v.z, v.w);
    } else if (b < 6266) {
        packw_body(W1l, W1r, wp1, (b - 6250) * 256 + tid);
    } else if (b < 6282) {
        packw_body(W2l, W2r, wp2, (b - 6266) * 256 + tid);
    } else if (b < 6286) {
        int t = (b - 6282) * 256 + tid;  // < 1024
        int l = t & 63, n = (t >> 6) & 3, ks = t >> 8;
        int kg = l >> 4, col = 16 * n + (l & 15);
        uint out[4];
#pragma unroll
        for (int jj = 0; jj < 4; ++jj) {
            int k = 32 * ks + 8 * kg + 2 * jj;
            out[jj] = (uint)f2bf(Wc[k * 64 + col]) | ((uint)f2bf(Wc[(k + 1) * 64 + col]) << 16);
        }
        *(uint4*)(wpc + (long long)t * 8) = make_uint4(out[0], out[1], out[2], out[3]);
    } else {
        gcnt[tid] = 0;  // b == 6286
    }
}

// ---------------- gather (fp8) into LDS: 8-lane group per node, 8-deep ILP ----------------
// BM = 32 rows/block, 32 groups of 8 lanes, one node each. Each lane owns 16
// contiguous channels (uint4 = 16 fp8). A wave's load instruction fetches 8
// different rows at once; 8-deep unroll => 64 rows in flight per wave.
// Over-read indices (pad garbage) are unsigned-clamped and zero-masked.
__device__ __forceinline__ void gather_stage32(
    const int* __restrict__ offs, const int* __restrict__ offe,
    const int* __restrict__ ssrc, const unsigned char* __restrict__ x8,
    const ushort* __restrict__ xbf,
    char* a_sh, int row0, int tid) {
    int r = tid >> 3;       // group = node row 0..31
    int l7 = tid & 7;       // channels 16*l7 .. 16*l7+15
    int node = row0 + r;
    int s0 = 0, s1 = 0;
    if (node < NN) { s0 = offs[node]; s1 = offe[node]; }
    float a[16];
#pragma unroll
    for (int k = 0; k < 16; ++k) a[k] = 0.f;
    int j = s0;
    if (j < s1) {
        // over-reads stay inside the bucket's CAP segment; garbage clamped+masked.
        uint4 iA = *(const uint4*)(ssrc + j);
        uint4 iB = *(const uint4*)(ssrc + j + 4);
        do {
            uint4 nA = *(const uint4*)(ssrc + j + 8);   // prefetch next iter
            uint4 nB = *(const uint4*)(ssrc + j + 12);
            uint4 v0 = ((const uint4*)(x8 + (long long)uclamp(iA.x) * CC))[l7];
            uint4 v1 = ((const uint4*)(x8 + (long long)uclamp(iA.y) * CC))[l7];
            uint4 v2 = ((const uint4*)(x8 + (long long)uclamp(iA.z) * CC))[l7];
            uint4 v3 = ((const uint4*)(x8 + (long long)uclamp(iA.w) * CC))[l7];
            uint4 v4 = ((const uint4*)(x8 + (long long)uclamp(iB.x) * CC))[l7];
            uint4 v5 = ((const uint4*)(x8 + (long long)uclamp(iB.y) * CC))[l7];
            uint4 v6 = ((const uint4*)(x8 + (long long)uclamp(iB.z) * CC))[l7];
            uint4 v7 = ((const uint4*)(x8 + (long long)uclamp(iB.w) * CC))[l7];
            int rem = s1 - j;
            {
                uint m = rem > 0 ? 0xffffffffu : 0u;  // rem>=1 in loop
                acc8_fp8(v0.x & m, v0.y & m, a);
                acc8_fp8(v0.z & m, v0.w & m, a + 8);
            }
            { uint m = rem > 1 ? 0xffffffffu : 0u;
              acc8_fp8(v1.x & m, v1.y & m, a); acc8_fp8(v1.z & m, v1.w & m, a + 8); }
            { uint m = rem > 2 ? 0xffffffffu : 0u;
              acc8_fp8(v2.x & m, v2.y & m, a); acc8_fp8(v2.z & m, v2.w & m, a + 8); }
            { uint m = rem > 3 ? 0xffffffffu : 0u;
              acc8_fp8(v3.x & m, v3.y & m, a); acc8_fp8(v3.z & m, v3.w & m, a + 8); }
            { uint m = rem > 4 ? 0xffffffffu : 0u;
              acc8_fp8(v4.x & m, v4.y & m, a); acc8_fp8(v4.z & m, v4.w & m, a + 8); }
            { uint m = rem > 5 ? 0xffffffffu : 0u;
              acc8_fp8(v5.x & m, v5.y & m, a); acc8_fp8(v5.z & m, v5.w & m, a + 8); }
            { uint m = rem > 6 ? 0xffffffffu : 0u;
              acc8_fp8(v6.x & m, v6.y & m, a); acc8_fp8(v6.z & m, v6.w & m, a + 8); }
            { uint m = rem > 7 ? 0xffffffffu : 0u;
              acc8_fp8(v7.x & m, v7.y & m, a); acc8_fp8(v7.z & m, v7.w & m, a + 8); }
            iA = nA; iB = nB;
            j += 8;
        } while (j < s1);
    }
    float dinv = 1.0f / fmaxf((float)(s1 - s0), 1.0f);
    uint4 o0, o1;
    o0.x = (uint)f2bf(a[0] * dinv)  | ((uint)f2bf(a[1] * dinv)  << 16);
    o0.y = (uint)f2bf(a[2] * dinv)  | ((uint)f2bf(a[3] * dinv)  << 16);
    o0.z = (uint)f2bf(a[4] * dinv)  | ((uint)f2bf(a[5] * dinv)  << 16);
    o0.w = (uint)f2bf(a[6] * dinv)  | ((uint)f2bf(a[7] * dinv)  << 16);
    o1.x = (uint)f2bf(a[8] * dinv)  | ((uint)f2bf(a[9] * dinv)  << 16);
    o1.y = (uint)f2bf(a[10] * dinv) | ((uint)f2bf(a[11] * dinv) << 16);
    o1.z = (uint)f2bf(a[12] * dinv) | ((uint)f2bf(a[13] * dinv) << 16);
    o1.w = (uint)f2bf(a[14] * dinv) | ((uint)f2bf(a[15] * dinv) << 16);
    int c0 = 2 * l7;  // 16B chunk indices within the row's 256B aggr half
    *(uint4*)(a_sh + r * 512 + ((c0 * 16) ^ ((r & 7) << 4))) = o0;
    *(uint4*)(a_sh + r * 512 + (((c0 + 1) * 16) ^ ((r & 7) << 4))) = o1;
    // stage self rows (bf16, linear): 32 rows x 16 chunks
#pragma unroll
    for (int it = 0; it < 2; ++it) {
        int idx = tid + it * 256;
        int rr = idx >> 4, c = idx & 15;
        int row = row0 + rr;
        uint4 v = make_uint4(0, 0, 0, 0);
        if (row < NN) v = ((const uint4*)(xbf + (long long)row * CC))[c];
        *(uint4*)(a_sh + rr * 512 + ((256 + c * 16) ^ ((rr & 7) << 4))) = v;
    }
}

// ---------------- fused gather + MFMA layer (BM=32, wave-split 2x2) ----------------
__global__ __launch_bounds__(256) void k_fused_layer(
    const int* __restrict__ offs, const int* __restrict__ offe,
    const int* __restrict__ ssrc, const unsigned char* __restrict__ x8,
    const ushort* __restrict__ xbf,
    const ushort* __restrict__ wp, const float* __restrict__ bias,
    ushort* __restrict__ hbf, unsigned char* __restrict__ h8) {
    __shared__ uint4 a_sh4[1024];  // 16KB
    char* a_sh = (char*)a_sh4;
    int row0 = blockIdx.x * 32;
    int tid = threadIdx.x;
    gather_stage32(offs, offe, ssrc, x8, xbf, a_sh, row0, tid);
    __syncthreads();

    int w = tid >> 6, l = tid & 63;
    int l15 = l & 15, kg = l >> 4;
    int wr = w >> 1, wc = w & 1;      // wave covers rows 16*wr.., cols 64*wc..
    int lrow = 16 * wr + l15;
    f32x4 acc[4];
#pragma unroll
    for (int n = 0; n < 4; ++n) {
        float b = bias[16 * (4 * wc + n) + l15];
        acc[n] = (f32x4){b, b, b, b};
    }
#pragma unroll
    for (int ks = 0; ks < 8; ++ks) {
        short8 af = *(const short8*)(a_sh + lrow * 512 + ((ks * 64 + kg * 16) ^ ((lrow & 7) << 4)));
#pragma unroll
        for (int n = 0; n < 4; ++n) {
            short8 bf = ((const short8*)wp)[(ks * 8 + 4 * wc + n) * 64 + l];
            acc[n] = __builtin_amdgcn_mfma_f32_16x16x32_bf16(af, bf, acc[n], 0, 0, 0);
        }
    }
#pragma unroll
    for (int n = 0; n < 4; ++n) {
        int col = 16 * (4 * wc + n) + l15;
#pragma unroll
        for (int r = 0; r < 4; ++r) {
            int row = row0 + 16 * wr + kg * 4 + r;
            if (row < NN) {
                float v = fmaxf(acc[n][r], 0.f);
                hbf[(long long)row * CC + col] = f2bf(v);
                h8[(long long)row * CC + col] =
                    (unsigned char)(__builtin_amdgcn_cvt_pk_fp8_f32(v, v, 0u, false) & 0xffu);
            }
        }
    }
}

// ---------------- fused gather + MFMA layer2 + classifier (BM=32) ----------------
__global__ __launch_bounds__(256) void k_fused_layer2_cls(
    const int* __restrict__ offs, const int* __restrict__ offe,
    const int* __restrict__ ssrc, const unsigned char* __restrict__ h8,
    const ushort* __restrict__ xbf,
    const ushort* __restrict__ wp2, const float* __restrict__ b2,
    const ushort* __restrict__ wpc, const float* __restrict__ bc,
    float* __restrict__ h2f, float* __restrict__ logits) {
    __shared__ uint4 a_sh4[1024];  // 16KB
    char* a_sh = (char*)a_sh4;
    int row0 = blockIdx.x * 32;
    int tid = threadIdx.x;
    gather_stage32(offs, offe, ssrc, h8, xbf, a_sh, row0, tid);
    __syncthreads();

    int w = tid >> 6, l = tid & 63;
    int l15 = l & 15, kg = l >> 4;
    int wr = w >> 1, wc = w & 1;
    int lrow = 16 * wr + l15;
    f32x4 acc[4];
#pragma unroll
    for (int n = 0; n < 4; ++n) {
        float b = b2[16 * (4 * wc + n) + l15];
        acc[n] = (f32x4){b, b, b, b};
    }
#pragma unroll
    for (int ks = 0; ks < 8; ++ks) {
        short8 af = *(const short8*)(a_sh + lrow * 512 + ((ks * 64 + kg * 16) ^ ((lrow & 7) << 4)));
#pragma unroll
        for (int n = 0; n < 4; ++n) {
            short8 bf = ((const short8*)wp2)[(ks * 8 + 4 * wc + n) * 64 + l];
            acc[n] = __builtin_amdgcn_mfma_f32_16x16x32_bf16(af, bf, acc[n], 0, 0, 0);
        }
    }
    __syncthreads();

    // epilogue: relu -> h2 f32 (global) + bf16 into cls LDS [32][256B] swizzled
#pragma unroll
    for (int n = 0; n < 4; ++n) {
        int col = 16 * (4 * wc + n) + l15;
#pragma unroll
        for (int r = 0; r < 4; ++r) {
            int lr = 16 * wr + kg * 4 + r;
            int row = row0 + lr;
            float v = fmaxf(acc[n][r], 0.f);
            if (row < NN) h2f[(long long)row * CC + col] = v;
            *(ushort*)(a_sh + lr * 256 + ((col * 2) ^ ((lr & 7) << 4))) = f2bf(v);
        }
    }
    __syncthreads();

    // classifier: logits = h2 @ Wc + bc  (K=128, N=64; wave covers 32 cols)
    f32x4 acc2[2];
#pragma unroll
    for (int n = 0; n < 2; ++n) {
        float b = bc[16 * (2 * wc + n) + l15];
        acc2[n] = (f32x4){b, b, b, b};
    }
#pragma unroll
    for (int ks = 0; ks < 4; ++ks) {
        short8 af = *(const short8*)(a_sh + lrow * 256 + ((ks * 64 + kg * 16) ^ ((lrow & 7) << 4)));
#pragma unroll
        for (int n = 0; n < 2; ++n) {
            short8 bf = ((const short8*)wpc)[(ks * 4 + 2 * wc + n) * 64 + l];
            acc2[n] = __builtin_amdgcn_mfma_f32_16x16x32_bf16(af, bf, acc2[n], 0, 0, 0);
        }
    }
#pragma unroll
    for (int n = 0; n < 2; ++n) {
        int col = 16 * (2 * wc + n) + l15;
#pragma unroll
        for (int r = 0; r < 4; ++r) {
            int row = row0 + 16 * wr + kg * 4 + r;
            if (row < NN) logits[(long long)row * OC + col] = acc2[n][r];
        }
    }
}

extern "C" void kernel_launch(void* const* d_in, const int* in_sizes, int n_in,
                              void* d_out, int out_size, void* d_ws, size_t ws_size,
                              hipStream_t stream) {
    const float* x_doc = (const float*)d_in[0];
    const int* ei = (const int*)d_in[2];
    const float* W1l = (const float*)d_in[4];
    const float* b1  = (const float*)d_in[5];
    const float* W1r = (const float*)d_in[6];
    const float* W2l = (const float*)d_in[7];
    const float* b2  = (const float*)d_in[8];
    const float* W2r = (const float*)d_in[9];
    const float* Wc  = (const float*)d_in[10];
    const float* bc  = (const float*)d_in[11];

    const int* src = ei;
    const int* dst = ei + EE;

    // workspace layout (16B-aligned segments)
    ushort* x_bf  = (ushort*)d_ws;                       // NN*CC ushort
    ushort* h1_bf = x_bf + (long long)NN * CC;           // NN*CC ushort
    unsigned char* x_f8  = (unsigned char*)(h1_bf + (long long)NN * CC);  // NN*CC bytes
    unsigned char* h1_f8 = x_f8 + (long long)NN * CC;    // NN*CC bytes
    ushort* wp1   = (ushort*)(h1_f8 + (long long)NN * CC); // 32768
    ushort* wp2   = wp1 + 32768;                         // 32768
    ushort* wpc   = wp2 + 32768;                         // 8192
    int* gcnt     = (int*)(wpc + 8192);                  // 256
    int* offs     = gcnt + 256;                          // NN (pad to 50176)
    int* offe     = offs + 50176;                        // NN (pad to 50176)
    int* ssrc     = offe + 50176;                        // NBKT*CAP
    uint* binned  = (uint*)(ssrc + NBKT * CAP);          // NBKT*CAP

    float* logits = (float*)d_out;                       // NN*OC
    float* h2f    = logits + (long long)NN * OC;         // NN*CC

    // prep (also zeros gcnt) -> bin -> fine
    k_prep<<<6287, 256, 0, stream>>>(x_doc, x_bf, x_f8, W1l, W1r, wp1,
                                     W2l, W2r, wp2, Wc, wpc, gcnt);
    k_bin<<<NBIN_BLK, 256, 0, stream>>>(src, dst, gcnt, binned);
    k_fine<<<NBKT, 256, 0, stream>>>(gcnt, binned, offs, offe, ssrc);

    // layer 1 (fp8 gather fused)
    k_fused_layer<<<(NN + 31) / 32, 256, 0, stream>>>(offs, offe, ssrc, x_f8, x_bf,
                                                      wp1, b1, h1_bf, h1_f8);

    // layer 2 + classifier (fp8 gather fused)
    k_fused_layer2_cls<<<(NN + 31) / 32, 256, 0, stream>>>(offs, offe, ssrc, h1_f8, h1_bf,
                                                           wp2, b2, wpc, bc, h2f, logits);
}